// Round 1
// baseline (787.102 us; speedup 1.0000x reference)
//
#include <hip/hip_runtime.h>
#include <math.h>

#define N_TOT  4096
#define C_DIM  64
#define P_DIM  512
#define SLOTS  (C_DIM * P_DIM)   // 32768 floats per sample
#define NC     4
#define NPAIRS 6

// ---------------------------------------------------------------------------
// K1: label histogram + zero the 6 pair accumulators (ws is poisoned 0xAA).
// Single block; trivial cost.
// ---------------------------------------------------------------------------
__global__ void count_zero_kernel(const int* __restrict__ labels,
                                  int* __restrict__ counts,
                                  float* __restrict__ pairacc) {
    __shared__ int h[NC];
    const int t = threadIdx.x;
    if (t < NC) h[t] = 0;
    if (t < NPAIRS) pairacc[t] = 0.0f;
    __syncthreads();
    for (int i = t; i < N_TOT; i += 256) {
        atomicAdd(&h[labels[i]], 1);
    }
    __syncthreads();
    if (t < NC) counts[t] = h[t];
}

// ---------------------------------------------------------------------------
// K2: per-(n-chunk, class, slot) partial sums.
// grid = (SLOTS/1024, nchunk), block = 256.  Each thread owns 4 consecutive
// slots (one float4) and loops over the chunk's n range.  Label is uniform
// across the wave each iteration -> readfirstlane + scalar branch, so the
// inner loop is ~1 dwordx4 load + 4 v_add per n.  Plain stores (each partial
// element written by exactly one thread) -> no atomics, no pre-zeroing.
// ---------------------------------------------------------------------------
__device__ __forceinline__ void accsel(int l, const float4 v,
                                       float4& a0, float4& a1,
                                       float4& a2, float4& a3) {
    if (l == 0)      { a0.x += v.x; a0.y += v.y; a0.z += v.z; a0.w += v.w; }
    else if (l == 1) { a1.x += v.x; a1.y += v.y; a1.z += v.z; a1.w += v.w; }
    else if (l == 2) { a2.x += v.x; a2.y += v.y; a2.z += v.z; a2.w += v.w; }
    else             { a3.x += v.x; a3.y += v.y; a3.z += v.z; a3.w += v.w; }
}

__global__ __launch_bounds__(256)
void partial_sums_kernel(const float* __restrict__ x,
                         const int* __restrict__ labels,
                         float* __restrict__ partial,
                         int nPerChunk) {
    extern __shared__ int lab[];   // nPerChunk ints
    const int t     = threadIdx.x;
    const int chunk = blockIdx.y;
    const int n0    = chunk * nPerChunk;

    for (int i = t; i < nPerChunk; i += 256) lab[i] = labels[n0 + i];
    __syncthreads();

    const int slot = blockIdx.x * 1024 + t * 4;
    float4 a0 = make_float4(0.f, 0.f, 0.f, 0.f);
    float4 a1 = a0, a2 = a0, a3 = a0;

    const float* xp = x + (size_t)n0 * SLOTS + slot;
    // nPerChunk = 4096/nchunk with nchunk a power of two <= 32  ->  >=128,
    // always a multiple of 4: no tail loop needed.
    for (int i = 0; i + 4 <= nPerChunk; i += 4) {
        float4 v0 = *(const float4*)(xp);
        float4 v1 = *(const float4*)(xp + SLOTS);
        float4 v2 = *(const float4*)(xp + 2 * (size_t)SLOTS);
        float4 v3 = *(const float4*)(xp + 3 * (size_t)SLOTS);
        xp += 4 * (size_t)SLOTS;
        int l0 = __builtin_amdgcn_readfirstlane(lab[i]);
        int l1 = __builtin_amdgcn_readfirstlane(lab[i + 1]);
        int l2 = __builtin_amdgcn_readfirstlane(lab[i + 2]);
        int l3 = __builtin_amdgcn_readfirstlane(lab[i + 3]);
        accsel(l0, v0, a0, a1, a2, a3);
        accsel(l1, v1, a0, a1, a2, a3);
        accsel(l2, v2, a0, a1, a2, a3);
        accsel(l3, v3, a0, a1, a2, a3);
    }

    float* o = partial + ((size_t)chunk * NC) * SLOTS + slot;
    *(float4*)(o)                     = a0;
    *(float4*)(o + SLOTS)             = a1;
    *(float4*)(o + 2 * (size_t)SLOTS) = a2;
    *(float4*)(o + 3 * (size_t)SLOTS) = a3;
}

// ---------------------------------------------------------------------------
// K3: reduce partials over chunks -> centers -> 6 pairwise sum-of-squared
// diffs, shuffle-reduced per wave, one atomicAdd per wave per pair.
// grid = SLOTS/256 = 128 blocks.
// ---------------------------------------------------------------------------
__global__ __launch_bounds__(256)
void pair_kernel(const float* __restrict__ partial,
                 const int* __restrict__ counts,
                 float* __restrict__ pairacc,
                 int nchunk) {
    const int slot = blockIdx.x * 256 + threadIdx.x;

    float s[NC];
#pragma unroll
    for (int k = 0; k < NC; ++k) {
        float a = 0.0f;
        for (int ch = 0; ch < nchunk; ++ch)
            a += partial[((size_t)ch * NC + k) * SLOTS + slot];
        s[k] = a;
    }

    float c[NC];
#pragma unroll
    for (int k = 0; k < NC; ++k)
        c[k] = s[k] / fmaxf((float)counts[k], 1.0f);

    float p[NPAIRS];
    {
        int pi = 0;
#pragma unroll
        for (int a_ = 0; a_ < NC; ++a_)
#pragma unroll
            for (int b_ = a_ + 1; b_ < NC; ++b_) {
                float d = c[a_] - c[b_];
                p[pi++] = d * d;
            }
    }

    const int lane = threadIdx.x & 63;
#pragma unroll
    for (int i = 0; i < NPAIRS; ++i) {
        float v = p[i];
        for (int off = 32; off > 0; off >>= 1)
            v += __shfl_down(v, off, 64);
        if (lane == 0) atomicAdd(&pairacc[i], v);
    }
}

// ---------------------------------------------------------------------------
// K4: final scalar.
// ---------------------------------------------------------------------------
__global__ void final_kernel(const float* __restrict__ pairacc,
                             float* __restrict__ out) {
    if (threadIdx.x == 0 && blockIdx.x == 0) {
        float s = 0.0f;
#pragma unroll
        for (int i = 0; i < NPAIRS; ++i) s += sqrtf(pairacc[i]);
        out[0] = s * (1.0f / 6.0f);
    }
}

// ---------------------------------------------------------------------------
extern "C" void kernel_launch(void* const* d_in, const int* in_sizes, int n_in,
                              void* d_out, int out_size, void* d_ws, size_t ws_size,
                              hipStream_t stream) {
    const float* x      = (const float*)d_in[0];
    const int*   labels = (const int*)d_in[1];
    float*       out    = (float*)d_out;

    // Workspace: partial[nchunk][NC][SLOTS] floats, then counts[4], pairacc[6].
    const size_t per = (size_t)NC * SLOTS * sizeof(float);   // 512 KiB per chunk
    int nchunk = 32;
    while (nchunk > 1 && (size_t)nchunk * per + 64 > ws_size) nchunk >>= 1;

    float* partial = (float*)d_ws;
    char*  tail    = (char*)d_ws + (size_t)nchunk * per;
    int*   counts  = (int*)tail;
    float* pairacc = (float*)(tail + 16);

    const int nPerChunk = N_TOT / nchunk;

    count_zero_kernel<<<1, 256, 0, stream>>>(labels, counts, pairacc);
    partial_sums_kernel<<<dim3(SLOTS / 1024, nchunk), 256,
                          nPerChunk * sizeof(int), stream>>>(x, labels, partial, nPerChunk);
    pair_kernel<<<SLOTS / 256, 256, 0, stream>>>(partial, counts, pairacc, nchunk);
    final_kernel<<<1, 64, 0, stream>>>(pairacc, out);
}

// Round 2
// 775.519 us; speedup vs baseline: 1.0149x; 1.0149x over previous
//
#include <hip/hip_runtime.h>
#include <math.h>

#define N_TOT  4096
#define C_DIM  64
#define P_DIM  512
#define SLOTS  (C_DIM * P_DIM)   // 32768 floats per sample
#define NC     4
#define NPAIRS 6
#define NCHUNK 32
#define NPER   (N_TOT / NCHUNK)  // 128 samples per chunk (compile-time)

// ---------------------------------------------------------------------------
// K1: label histogram + zero the 6 pair accumulators (ws is poisoned 0xAA).
// ---------------------------------------------------------------------------
__global__ void count_zero_kernel(const int* __restrict__ labels,
                                  int* __restrict__ counts,
                                  float* __restrict__ pairacc) {
    __shared__ int h[NC];
    const int t = threadIdx.x;
    if (t < NC) h[t] = 0;
    if (t < NPAIRS) pairacc[t] = 0.0f;
    __syncthreads();
    for (int i = t; i < N_TOT; i += 256) {
        atomicAdd(&h[labels[i]], 1);
    }
    __syncthreads();
    if (t < NC) counts[t] = h[t];
}

// ---------------------------------------------------------------------------
// K2: per-(n-chunk, class, slot) partial sums.  grid = (32, 32), block 256.
// Each thread owns one float4 of the 32768-slot sample and streams NPER=128
// samples, 8 dwordx4 in flight per wave (MLP ~128 KB/CU at 16 waves/CU).
// Label is wave-uniform per sample -> readfirstlane + scalar branch chain:
// 4 v_add per 16 B loaded, VALU stays cold, HBM saturates.
// Plain stores (each partial element has exactly one writer) -> no atomics.
// ---------------------------------------------------------------------------
__device__ __forceinline__ void accsel(int l, const float4 v,
                                       float4& a0, float4& a1,
                                       float4& a2, float4& a3) {
    if (l == 0)      { a0.x += v.x; a0.y += v.y; a0.z += v.z; a0.w += v.w; }
    else if (l == 1) { a1.x += v.x; a1.y += v.y; a1.z += v.z; a1.w += v.w; }
    else if (l == 2) { a2.x += v.x; a2.y += v.y; a2.z += v.z; a2.w += v.w; }
    else             { a3.x += v.x; a3.y += v.y; a3.z += v.z; a3.w += v.w; }
}

__global__ __launch_bounds__(256)
void partial_sums_kernel(const float* __restrict__ x,
                         const int* __restrict__ labels,
                         float* __restrict__ partial) {
    __shared__ int lab[NPER];
    const int t     = threadIdx.x;
    const int chunk = blockIdx.y;
    const int n0    = chunk * NPER;

    for (int i = t; i < NPER; i += 256) lab[i] = labels[n0 + i];
    __syncthreads();

    const int slot = blockIdx.x * 1024 + t * 4;
    float4 a0 = make_float4(0.f, 0.f, 0.f, 0.f);
    float4 a1 = a0, a2 = a0, a3 = a0;

    const float* xp = x + (size_t)n0 * SLOTS + slot;
    for (int i = 0; i < NPER; i += 8) {
        float4 v[8];
#pragma unroll
        for (int j = 0; j < 8; ++j)
            v[j] = *(const float4*)(xp + (size_t)j * SLOTS);
        xp += 8 * (size_t)SLOTS;
#pragma unroll
        for (int j = 0; j < 8; ++j) {
            int l = __builtin_amdgcn_readfirstlane(lab[i + j]);
            accsel(l, v[j], a0, a1, a2, a3);
        }
    }

    float* o = partial + ((size_t)chunk * NC) * SLOTS + slot;
    *(float4*)(o)                     = a0;
    *(float4*)(o + SLOTS)             = a1;
    *(float4*)(o + 2 * (size_t)SLOTS) = a2;
    *(float4*)(o + 3 * (size_t)SLOTS) = a3;
}

// ---------------------------------------------------------------------------
// K3: reduce partials over chunks -> centers -> 6 pairwise sum-of-squared
// diffs, shuffle-reduced per wave, one atomicAdd per wave per pair.
// grid = SLOTS/256 = 128 blocks; reads 16 MB (~3 us).
// ---------------------------------------------------------------------------
__global__ __launch_bounds__(256)
void pair_kernel(const float* __restrict__ partial,
                 const int* __restrict__ counts,
                 float* __restrict__ pairacc) {
    const int slot = blockIdx.x * 256 + threadIdx.x;

    float s[NC];
#pragma unroll
    for (int k = 0; k < NC; ++k) {
        float a = 0.0f;
#pragma unroll 4
        for (int ch = 0; ch < NCHUNK; ++ch)
            a += partial[((size_t)ch * NC + k) * SLOTS + slot];
        s[k] = a;
    }

    float c[NC];
#pragma unroll
    for (int k = 0; k < NC; ++k)
        c[k] = s[k] / fmaxf((float)counts[k], 1.0f);

    float p[NPAIRS];
    {
        int pi = 0;
#pragma unroll
        for (int a_ = 0; a_ < NC; ++a_)
#pragma unroll
            for (int b_ = a_ + 1; b_ < NC; ++b_) {
                float d = c[a_] - c[b_];
                p[pi++] = d * d;
            }
    }

    const int lane = threadIdx.x & 63;
#pragma unroll
    for (int i = 0; i < NPAIRS; ++i) {
        float v = p[i];
        for (int off = 32; off > 0; off >>= 1)
            v += __shfl_down(v, off, 64);
        if (lane == 0) atomicAdd(&pairacc[i], v);
    }
}

// ---------------------------------------------------------------------------
// K4: final scalar.
// ---------------------------------------------------------------------------
__global__ void final_kernel(const float* __restrict__ pairacc,
                             float* __restrict__ out) {
    if (threadIdx.x == 0 && blockIdx.x == 0) {
        float s = 0.0f;
#pragma unroll
        for (int i = 0; i < NPAIRS; ++i) s += sqrtf(pairacc[i]);
        out[0] = s * (1.0f / 6.0f);
    }
}

// ---------------------------------------------------------------------------
extern "C" void kernel_launch(void* const* d_in, const int* in_sizes, int n_in,
                              void* d_out, int out_size, void* d_ws, size_t ws_size,
                              hipStream_t stream) {
    const float* x      = (const float*)d_in[0];
    const int*   labels = (const int*)d_in[1];
    float*       out    = (float*)d_out;

    // Workspace: partial[NCHUNK][NC][SLOTS] floats (16 MiB), then counts[4],
    // pairacc[6].
    const size_t per = (size_t)NC * SLOTS * sizeof(float);   // 512 KiB per chunk
    float* partial = (float*)d_ws;
    char*  tail    = (char*)d_ws + (size_t)NCHUNK * per;
    int*   counts  = (int*)tail;
    float* pairacc = (float*)(tail + 16);

    count_zero_kernel<<<1, 256, 0, stream>>>(labels, counts, pairacc);
    partial_sums_kernel<<<dim3(SLOTS / 1024, NCHUNK), 256, 0, stream>>>(x, labels, partial);
    pair_kernel<<<SLOTS / 256, 256, 0, stream>>>(partial, counts, pairacc);
    final_kernel<<<1, 64, 0, stream>>>(pairacc, out);
}

// Round 3
// 716.812 us; speedup vs baseline: 1.0981x; 1.0819x over previous
//
#include <hip/hip_runtime.h>
#include <math.h>

#define N_TOT  4096
#define C_DIM  64
#define P_DIM  512
#define SLOTS  (C_DIM * P_DIM)   // 32768 floats per sample
#define NC     4
#define NPAIRS 6
#define NCHUNK 32
#define NPER   (N_TOT / NCHUNK)  // 128 samples per chunk (compile-time)
#define K3_BLOCKS (SLOTS / 256)  // 128

// ---------------------------------------------------------------------------
// K2: per-(n-chunk, class, slot) partial sums.  grid = (32, 32), block 256.
// Each thread owns one float4 of the 32768-slot sample and streams NPER=128
// samples.  Labels are wave-uniform -> readfirstlane + scalar 0/1 masks
// (s_cmp + s_cselect), accumulate with v_fma(v, s_mask, acc).  NO branches
// in the K-loop: LLVM can group the 8 dwordx4 loads and pipeline across
// iterations.  Plain stores (single writer per element) -> no atomics, no
// pre-zeroed ws needed.
// ---------------------------------------------------------------------------
__global__ __launch_bounds__(256)
void partial_sums_kernel(const float* __restrict__ x,
                         const int* __restrict__ labels,
                         float* __restrict__ partial) {
    __shared__ int lab[NPER];
    const int t     = threadIdx.x;
    const int chunk = blockIdx.y;
    const int n0    = chunk * NPER;

    for (int i = t; i < NPER; i += 256) lab[i] = labels[n0 + i];
    __syncthreads();

    const int slot = blockIdx.x * 1024 + t * 4;
    float4 a0 = make_float4(0.f, 0.f, 0.f, 0.f);
    float4 a1 = a0, a2 = a0, a3 = a0;

    const float* xp = x + (size_t)n0 * SLOTS + slot;
    for (int i = 0; i < NPER; i += 8) {
        float4 v[8];
#pragma unroll
        for (int j = 0; j < 8; ++j)
            v[j] = *(const float4*)(xp + (size_t)j * SLOTS);
        xp += 8 * (size_t)SLOTS;
#pragma unroll
        for (int j = 0; j < 8; ++j) {
            const int l = __builtin_amdgcn_readfirstlane(lab[i + j]);
            const float m0 = (l == 0) ? 1.0f : 0.0f;
            const float m1 = (l == 1) ? 1.0f : 0.0f;
            const float m2 = (l == 2) ? 1.0f : 0.0f;
            const float m3 = (l == 3) ? 1.0f : 0.0f;
            a0.x = fmaf(v[j].x, m0, a0.x); a0.y = fmaf(v[j].y, m0, a0.y);
            a0.z = fmaf(v[j].z, m0, a0.z); a0.w = fmaf(v[j].w, m0, a0.w);
            a1.x = fmaf(v[j].x, m1, a1.x); a1.y = fmaf(v[j].y, m1, a1.y);
            a1.z = fmaf(v[j].z, m1, a1.z); a1.w = fmaf(v[j].w, m1, a1.w);
            a2.x = fmaf(v[j].x, m2, a2.x); a2.y = fmaf(v[j].y, m2, a2.y);
            a2.z = fmaf(v[j].z, m2, a2.z); a2.w = fmaf(v[j].w, m2, a2.w);
            a3.x = fmaf(v[j].x, m3, a3.x); a3.y = fmaf(v[j].y, m3, a3.y);
            a3.z = fmaf(v[j].z, m3, a3.z); a3.w = fmaf(v[j].w, m3, a3.w);
        }
    }

    float* o = partial + ((size_t)chunk * NC) * SLOTS + slot;
    *(float4*)(o)                     = a0;
    *(float4*)(o + SLOTS)             = a1;
    *(float4*)(o + 2 * (size_t)SLOTS) = a2;
    *(float4*)(o + 3 * (size_t)SLOTS) = a3;
}

// ---------------------------------------------------------------------------
// K3: per-block redundant label histogram (16 KB, L2-hit), reduce partials
// over chunks -> centers -> 6 pairwise squared-diff sums, block-reduce, one
// plain store of 6 floats per block.  No atomics, no init dependency.
// grid = 128 blocks x 256 threads.
// ---------------------------------------------------------------------------
__global__ __launch_bounds__(256)
void pair_kernel(const float* __restrict__ partial,
                 const int* __restrict__ labels,
                 float* __restrict__ pairpart) {
    const int t    = threadIdx.x;
    const int wave = t >> 6;
    const int lane = t & 63;

    // -- histogram of all 4096 labels, block-local --
    int cnt[NC] = {0, 0, 0, 0};
    for (int i = t; i < N_TOT; i += 256) {
        const int l = labels[i];
#pragma unroll
        for (int k = 0; k < NC; ++k) cnt[k] += (l == k) ? 1 : 0;
    }
    __shared__ int shc[4][NC];
#pragma unroll
    for (int k = 0; k < NC; ++k) {
        int v = cnt[k];
        for (int off = 32; off > 0; off >>= 1) v += __shfl_down(v, off, 64);
        if (lane == 0) shc[wave][k] = v;
    }
    __syncthreads();
    float inv[NC];
#pragma unroll
    for (int k = 0; k < NC; ++k) {
        const int c = shc[0][k] + shc[1][k] + shc[2][k] + shc[3][k];
        inv[k] = 1.0f / fmaxf((float)c, 1.0f);
    }

    // -- per-slot center values --
    const int slot = blockIdx.x * 256 + t;
    float c[NC];
#pragma unroll
    for (int k = 0; k < NC; ++k) {
        float a = 0.0f;
#pragma unroll 4
        for (int ch = 0; ch < NCHUNK; ++ch)
            a += partial[((size_t)ch * NC + k) * SLOTS + slot];
        c[k] = a * inv[k];
    }

    // -- 6 pairwise squared diffs, block-reduced --
    float p[NPAIRS];
    {
        int pi = 0;
#pragma unroll
        for (int a_ = 0; a_ < NC; ++a_)
#pragma unroll
            for (int b_ = a_ + 1; b_ < NC; ++b_) {
                const float d = c[a_] - c[b_];
                p[pi++] = d * d;
            }
    }
    __shared__ float shp[4][NPAIRS];
#pragma unroll
    for (int i = 0; i < NPAIRS; ++i) {
        float v = p[i];
        for (int off = 32; off > 0; off >>= 1) v += __shfl_down(v, off, 64);
        if (lane == 0) shp[wave][i] = v;
    }
    __syncthreads();
    if (t < NPAIRS)
        pairpart[blockIdx.x * NPAIRS + t] =
            shp[0][t] + shp[1][t] + shp[2][t] + shp[3][t];
}

// ---------------------------------------------------------------------------
// K4: reduce 128 x 6 pair partials, sqrt, average.  1 block x 128 threads.
// ---------------------------------------------------------------------------
__global__ __launch_bounds__(128)
void final_kernel(const float* __restrict__ pairpart,
                  float* __restrict__ out) {
    const int t    = threadIdx.x;
    const int wave = t >> 6;
    const int lane = t & 63;

    float p[NPAIRS];
#pragma unroll
    for (int i = 0; i < NPAIRS; ++i) p[i] = pairpart[t * NPAIRS + i];

    __shared__ float shp[2][NPAIRS];
#pragma unroll
    for (int i = 0; i < NPAIRS; ++i) {
        float v = p[i];
        for (int off = 32; off > 0; off >>= 1) v += __shfl_down(v, off, 64);
        if (lane == 0) shp[wave][i] = v;
    }
    __syncthreads();
    if (t == 0) {
        float s = 0.0f;
#pragma unroll
        for (int i = 0; i < NPAIRS; ++i) s += sqrtf(shp[0][i] + shp[1][i]);
        out[0] = s * (1.0f / 6.0f);
    }
}

// ---------------------------------------------------------------------------
extern "C" void kernel_launch(void* const* d_in, const int* in_sizes, int n_in,
                              void* d_out, int out_size, void* d_ws, size_t ws_size,
                              hipStream_t stream) {
    const float* x      = (const float*)d_in[0];
    const int*   labels = (const int*)d_in[1];
    float*       out    = (float*)d_out;

    // ws layout: partial[NCHUNK][NC][SLOTS] floats (16 MiB), then
    // pairpart[K3_BLOCKS][NPAIRS].
    float* partial  = (float*)d_ws;
    float* pairpart = (float*)((char*)d_ws +
                               (size_t)NCHUNK * NC * SLOTS * sizeof(float));

    partial_sums_kernel<<<dim3(SLOTS / 1024, NCHUNK), 256, 0, stream>>>(x, labels, partial);
    pair_kernel<<<K3_BLOCKS, 256, 0, stream>>>(partial, labels, pairpart);
    final_kernel<<<1, 128, 0, stream>>>(pairpart, out);
}